// Round 1
// baseline (138.185 us; speedup 1.0000x reference)
//
#include <hip/hip_runtime.h>

// WaveletLayer: per-row pipeline on [4096, 4096] fp32
//   h = x * diag_b
//   h = DWT3_haar(h)          // packet layout [cA3|cD3|cD2|cD1]
//   h = h[perm] * diag_g
//   h = DWT3_haar(h)
//   out = h * diag_s
//
// Haar analysis (pad=0, stride 2, filt len 2, cross-correlation):
//   cA[t] = (v[2t] + v[2t+1]) * INV_SQRT2
//   cD[t] = (v[2t] - v[2t+1]) * INV_SQRT2
// Level l maps buf[0:len] -> cA in buf[0:len/2], cD in buf[len/2:len].
// After 3 levels starting at len=D this yields exactly [cA3|cD3|cD2|cD1].

#define D   4096
#define NT  256
#define VPT (D / NT)   // 16 elements per thread

static __device__ __forceinline__ constexpr float inv_sqrt2() {
    return 0.70710678118654752440f;
}

__global__ __launch_bounds__(NT) void wavelet_row_kernel(
    const float* __restrict__ x,
    const float* __restrict__ diag_s,
    const float* __restrict__ diag_g,
    const float* __restrict__ diag_b,
    const int*   __restrict__ perm,
    float*       __restrict__ out)
{
    __shared__ float buf[D];

    const int tid = threadIdx.x;
    const size_t row = blockIdx.x;
    const float* xr = x + row * (size_t)D;
    float* orow = out + row * (size_t)D;

    // ---- load row * diag_b (float4 vectorized, coalesced) ----
    {
        const float4* x4 = (const float4*)xr;
        const float4* b4 = (const float4*)diag_b;
        float4* s4 = (float4*)buf;
        for (int i = tid; i < D / 4; i += NT) {
            float4 v = x4[i];
            float4 b = b4[i];
            v.x *= b.x; v.y *= b.y; v.z *= b.z; v.w *= b.w;
            s4[i] = v;
        }
    }
    __syncthreads();

    // ---- DWT #1: 3 in-place butterfly levels ----
    #pragma unroll
    for (int lvl = 0; lvl < 3; ++lvl) {
        const int len  = D >> lvl;
        const int half = len >> 1;       // 2048, 1024, 512 — all multiples of NT
        float a[VPT / 2], b[VPT / 2];
        int cnt = 0;
        for (int p = tid; p < half; p += NT) {
            a[cnt] = buf[2 * p];         // stride-2 LDS read: 2-way = free
            b[cnt] = buf[2 * p + 1];
            ++cnt;
        }
        __syncthreads();
        cnt = 0;
        for (int p = tid; p < half; p += NT) {
            buf[p]        = (a[cnt] + b[cnt]) * inv_sqrt2();
            buf[half + p] = (a[cnt] - b[cnt]) * inv_sqrt2();
            ++cnt;
        }
        __syncthreads();
    }

    // ---- permutation gather + diag_g (register-staged, in place) ----
    {
        int   pj[VPT];
        float gv[VPT];
        #pragma unroll
        for (int k = 0; k < VPT; ++k) {
            const int j = tid + k * NT;          // coalesced global reads
            pj[k] = perm[j];
        }
        #pragma unroll
        for (int k = 0; k < VPT; ++k) {
            const int j = tid + k * NT;
            gv[k] = buf[pj[k]] * diag_g[j];      // random LDS gather
        }
        __syncthreads();
        #pragma unroll
        for (int k = 0; k < VPT; ++k) {
            buf[tid + k * NT] = gv[k];
        }
        __syncthreads();
    }

    // ---- DWT #2: same 3 levels ----
    #pragma unroll
    for (int lvl = 0; lvl < 3; ++lvl) {
        const int len  = D >> lvl;
        const int half = len >> 1;
        float a[VPT / 2], b[VPT / 2];
        int cnt = 0;
        for (int p = tid; p < half; p += NT) {
            a[cnt] = buf[2 * p];
            b[cnt] = buf[2 * p + 1];
            ++cnt;
        }
        __syncthreads();
        cnt = 0;
        for (int p = tid; p < half; p += NT) {
            buf[p]        = (a[cnt] + b[cnt]) * inv_sqrt2();
            buf[half + p] = (a[cnt] - b[cnt]) * inv_sqrt2();
            ++cnt;
        }
        __syncthreads();
    }

    // ---- store row * diag_s (float4 vectorized, coalesced) ----
    {
        const float4* s4 = (const float4*)buf;
        const float4* d4 = (const float4*)diag_s;
        float4* o4 = (float4*)orow;
        for (int i = tid; i < D / 4; i += NT) {
            float4 v = s4[i];
            float4 s = d4[i];
            v.x *= s.x; v.y *= s.y; v.z *= s.z; v.w *= s.w;
            o4[i] = v;
        }
    }
}

extern "C" void kernel_launch(void* const* d_in, const int* in_sizes, int n_in,
                              void* d_out, int out_size, void* d_ws, size_t ws_size,
                              hipStream_t stream) {
    // setup_inputs() order: x, diag_s, diag_g, diag_b, dec_lo, dec_hi, perm, scales
    const float* x      = (const float*)d_in[0];
    const float* diag_s = (const float*)d_in[1];
    const float* diag_g = (const float*)d_in[2];
    const float* diag_b = (const float*)d_in[3];
    // d_in[4]/d_in[5]: Haar filters (hard-coded), d_in[7]: scales=3 (hard-coded)
    const int* perm     = (const int*)d_in[6];
    float* out          = (float*)d_out;

    const int B = 4096;
    wavelet_row_kernel<<<B, NT, 0, stream>>>(x, diag_s, diag_g, diag_b, perm, out);
}